// Round 1
// baseline (459.367 us; speedup 1.0000x reference)
//
#include <hip/hip_runtime.h>
#include <stdint.h>
#include <stddef.h>

// BinarizeLinearWithFoldedBN on MI355X.
// out[b,o] = (dot(sign(x[b,:]), sign(w[o,:])) - mean[o]) / sqrt(var[o]+eps) * gamma[o] + beta[o]
// Implemented as XOR-popcount GEMM over packed sign bits:
//   dot = IN - 2*popc(xbits ^ wbits)
// ws layout: XP[B*KW] u32 | WP[OUT*KW] u32 | scale[OUT] f32 | bias[OUT] f32  (~6.3 MB)

#define BN_EPS 1e-5f

// ---------------- pack: f32 sign bits -> u32 words (32 consecutive elems/word) ----
__global__ void pack_sign_kernel(const uint32_t* __restrict__ in,
                                 uint32_t* __restrict__ outp, int nwords) {
  int w = blockIdx.x * blockDim.x + threadIdx.x;
  if (w >= nwords) return;
  const uint4* p = reinterpret_cast<const uint4*>(in) + (size_t)w * 8;
  uint32_t bits = 0;
#pragma unroll
  for (int i = 0; i < 8; ++i) {
    uint4 u = p[i];
    bits |= (u.x >> 31) << (i * 4 + 0);
    bits |= (u.y >> 31) << (i * 4 + 1);
    bits |= (u.z >> 31) << (i * 4 + 2);
    bits |= (u.w >> 31) << (i * 4 + 3);
  }
  outp[w] = bits;
}

// ---------------- fold BN into scale/bias ----------------
__global__ void bn_prep_kernel(const float* __restrict__ g, const float* __restrict__ b,
                               const float* __restrict__ m, const float* __restrict__ v,
                               float* __restrict__ scale, float* __restrict__ bias, int n) {
  int i = blockIdx.x * blockDim.x + threadIdx.x;
  if (i >= n) return;
  float s = g[i] * rsqrtf(v[i] + BN_EPS);
  scale[i] = s;
  bias[i] = b[i] - m[i] * s;
}

// ---------------- popcount GEMM ----------------
// Block tile 128x128, 256 threads, 8x8 outputs/thread.
// LDS is K-major: xs[kk][row], ws[kk][col] so per-kk reads are bank-conflict-free
// uint4 reads (rows {0,8,16,24}+4g across ty-lanes -> distinct banks; cols tx*4 -> 2-way, free).
#define BM 128
#define BNT 128
#define KS 16
#define TM 8
#define TN 8

__global__ __launch_bounds__(256) void popc_gemm_kernel(
    const uint32_t* __restrict__ XP, const uint32_t* __restrict__ WP,
    const float* __restrict__ scale, const float* __restrict__ bias,
    float* __restrict__ out, int Bdim, int OUT, int KW) {
  __shared__ __align__(16) uint32_t xs[KS][BM];
  __shared__ __align__(16) uint32_t wsm[KS][BNT];

  const int tid = threadIdx.x;
  const int tx = tid & 15;        // 0..15 -> col groups
  const int ty = tid >> 4;        // 0..15 -> row group (8 rows each)
  const int row0 = blockIdx.y * BM;
  const int col0 = blockIdx.x * BNT;

  // staging assignment: each thread loads 8 words of X and 8 words of W
  const int lrow = tid >> 1;      // 0..127
  const int h = tid & 1;          // which half of the 16 K-words
  const uint32_t* xg = XP + (size_t)(row0 + lrow) * KW + h * 8;
  const uint32_t* wg = WP + (size_t)(col0 + lrow) * KW + h * 8;

  uint32_t acc[TM][TN];
#pragma unroll
  for (int i = 0; i < TM; ++i)
#pragma unroll
    for (int j = 0; j < TN; ++j) acc[i][j] = 0u;

  for (int k0 = 0; k0 < KW; k0 += KS) {
    // global -> regs (L2-resident after first pass; 6 MB total packed data)
    uint4 xv0 = *reinterpret_cast<const uint4*>(xg + k0);
    uint4 xv1 = *reinterpret_cast<const uint4*>(xg + k0 + 4);
    uint4 wv0 = *reinterpret_cast<const uint4*>(wg + k0);
    uint4 wv1 = *reinterpret_cast<const uint4*>(wg + k0 + 4);

    __syncthreads();  // previous compute done before overwrite
    // scatter to K-major LDS (2-way bank aliasing only -> free)
    xs[h * 8 + 0][lrow] = xv0.x;
    xs[h * 8 + 1][lrow] = xv0.y;
    xs[h * 8 + 2][lrow] = xv0.z;
    xs[h * 8 + 3][lrow] = xv0.w;
    xs[h * 8 + 4][lrow] = xv1.x;
    xs[h * 8 + 5][lrow] = xv1.y;
    xs[h * 8 + 6][lrow] = xv1.z;
    xs[h * 8 + 7][lrow] = xv1.w;
    wsm[h * 8 + 0][lrow] = wv0.x;
    wsm[h * 8 + 1][lrow] = wv0.y;
    wsm[h * 8 + 2][lrow] = wv0.z;
    wsm[h * 8 + 3][lrow] = wv0.w;
    wsm[h * 8 + 4][lrow] = wv1.x;
    wsm[h * 8 + 5][lrow] = wv1.y;
    wsm[h * 8 + 6][lrow] = wv1.z;
    wsm[h * 8 + 7][lrow] = wv1.w;
    __syncthreads();

#pragma unroll 4
    for (int kk = 0; kk < KS; ++kk) {
      uint4 a0 = *reinterpret_cast<const uint4*>(&xs[kk][ty * 8]);
      uint4 a1 = *reinterpret_cast<const uint4*>(&xs[kk][ty * 8 + 4]);
      uint4 b0 = *reinterpret_cast<const uint4*>(&wsm[kk][tx * 4]);
      uint4 b1 = *reinterpret_cast<const uint4*>(&wsm[kk][tx * 4 + 64]);
      uint32_t xr[TM] = {a0.x, a0.y, a0.z, a0.w, a1.x, a1.y, a1.z, a1.w};
      uint32_t wr[TN] = {b0.x, b0.y, b0.z, b0.w, b1.x, b1.y, b1.z, b1.w};
#pragma unroll
      for (int i = 0; i < TM; ++i)
#pragma unroll
        for (int j = 0; j < TN; ++j)
          acc[i][j] += (uint32_t)__popc(xr[i] ^ wr[j]);
    }
  }

  // epilogue: out = (IN - 2*popc) * scale + bias
  const float IN_total = (float)(KW * 32);
  float sc[TN], bi[TN];
#pragma unroll
  for (int j = 0; j < TN; ++j) {
    int c = col0 + ((j >> 2) * 64) + tx * 4 + (j & 3);
    sc[j] = scale[c];
    bi[j] = bias[c];
  }
#pragma unroll
  for (int i = 0; i < TM; ++i) {
    int r = row0 + ty * 8 + i;
    float4 v0, v1;
    v0.x = fmaf(IN_total - 2.0f * (float)acc[i][0], sc[0], bi[0]);
    v0.y = fmaf(IN_total - 2.0f * (float)acc[i][1], sc[1], bi[1]);
    v0.z = fmaf(IN_total - 2.0f * (float)acc[i][2], sc[2], bi[2]);
    v0.w = fmaf(IN_total - 2.0f * (float)acc[i][3], sc[3], bi[3]);
    v1.x = fmaf(IN_total - 2.0f * (float)acc[i][4], sc[4], bi[4]);
    v1.y = fmaf(IN_total - 2.0f * (float)acc[i][5], sc[5], bi[5]);
    v1.z = fmaf(IN_total - 2.0f * (float)acc[i][6], sc[6], bi[6]);
    v1.w = fmaf(IN_total - 2.0f * (float)acc[i][7], sc[7], bi[7]);
    float* orow = out + (size_t)r * OUT;
    *reinterpret_cast<float4*>(orow + col0 + tx * 4) = v0;
    *reinterpret_cast<float4*>(orow + col0 + 64 + tx * 4) = v1;
  }
}

extern "C" void kernel_launch(void* const* d_in, const int* in_sizes, int n_in,
                              void* d_out, int out_size, void* d_ws, size_t ws_size,
                              hipStream_t stream) {
  const float* x = (const float*)d_in[0];
  const float* w = (const float*)d_in[1];
  const float* gamma = (const float*)d_in[2];
  const float* beta = (const float*)d_in[3];
  const float* mean = (const float*)d_in[4];
  const float* var = (const float*)d_in[5];
  float* out = (float*)d_out;

  const int OUT = in_sizes[2];              // 4096
  const int IN = in_sizes[1] / OUT;         // 4096
  const int B = in_sizes[0] / IN;           // 8192
  const int KW = IN / 32;                   // 128 packed words per row

  uint32_t* xp = (uint32_t*)d_ws;
  uint32_t* wp = xp + (size_t)B * KW;
  float* scale = (float*)(wp + (size_t)OUT * KW);
  float* bias = scale + OUT;

  const int nwx = B * KW;
  const int nww = OUT * KW;
  pack_sign_kernel<<<(nwx + 255) / 256, 256, 0, stream>>>(
      (const uint32_t*)x, xp, nwx);
  pack_sign_kernel<<<(nww + 255) / 256, 256, 0, stream>>>(
      (const uint32_t*)w, wp, nww);
  bn_prep_kernel<<<(OUT + 255) / 256, 256, 0, stream>>>(
      gamma, beta, mean, var, scale, bias, OUT);

  dim3 grid(OUT / BNT, B / BM);
  popc_gemm_kernel<<<grid, 256, 0, stream>>>(xp, wp, scale, bias, out, B, OUT, KW);
}

// Round 2
// 226.342 us; speedup vs baseline: 2.0295x; 2.0295x over previous
//
#include <hip/hip_runtime.h>
#include <stdint.h>
#include <stddef.h>

// BinarizeLinearWithFoldedBN on MI355X (gfx950).
// out[b,o] = dot(sign(x[b,:]), sign(w[o,:])) * scale[o] + bias[o]
//   scale = gamma/sqrt(var+eps), bias = beta - mean*scale   (exact BN algebra)
// Primary path: i8 (+1/-1) MFMA GEMM via mfma_i32_16x16x64_i8 (exact i32 dot).
// Fallback path (if ws too small): XOR-popcount GEMM (round-1 kernel, known-passing).

#define BN_EPS 1e-5f

typedef int v4i __attribute__((ext_vector_type(4)));

// ---------------- BN fold ----------------
__global__ void bn_prep_kernel(const float* __restrict__ g, const float* __restrict__ b,
                               const float* __restrict__ m, const float* __restrict__ v,
                               float* __restrict__ scale, float* __restrict__ bias, int n) {
  int i = blockIdx.x * blockDim.x + threadIdx.x;
  if (i >= n) return;
  float s = g[i] * rsqrtf(v[i] + BN_EPS);
  scale[i] = s;
  bias[i] = b[i] - m[i] * s;
}

// ---------------- pack f32 signs -> i8 +1/-1 ----------------
// thread handles 16 floats (64B read) -> 16 i8 (16B write)
__global__ __launch_bounds__(256) void pack_sign_i8_kernel(
    const uint4* __restrict__ in, uint4* __restrict__ outp, int n16) {
  int t = blockIdx.x * blockDim.x + threadIdx.x;
  if (t >= n16) return;
  const uint4* p = in + (size_t)t * 4;
  uint32_t w[4];
#pragma unroll
  for (int i = 0; i < 4; ++i) {
    uint4 u = p[i];
    // byte = 0x01 (non-neg) or 0xFF (neg): 0x01 ^ (sign ? 0xFE : 0x00)
    uint32_t m = (((uint32_t)((int)u.x >> 31)) & 0xFEu)
               | ((((uint32_t)((int)u.y >> 31)) & 0xFEu) << 8)
               | ((((uint32_t)((int)u.z >> 31)) & 0xFEu) << 16)
               | ((((uint32_t)((int)u.w >> 31)) & 0xFEu) << 24);
    w[i] = 0x01010101u ^ m;
  }
  uint4 o; o.x = w[0]; o.y = w[1]; o.z = w[2]; o.w = w[3];
  outp[t] = o;
}

// ---------------- i8 MFMA GEMM (m97-style 128x128 tile, 4 waves, 2-barrier) ----------
// A8: [M][K] i8, B8: [N][K] i8 (both row-major over K). BK = 64 bytes per step.
// LDS granule swizzle: 16B granule g of row r stored at g ^ ((r>>1)&3); applied on
// BOTH the pre-swizzled global_load_lds source and the ds_read_b128 fragment read.
#define TILE 128
#define BKB 64

__global__ __launch_bounds__(256) void bgemm_i8_kernel(
    const int8_t* __restrict__ A8, const int8_t* __restrict__ B8,
    const float* __restrict__ scale, const float* __restrict__ bias,
    float* __restrict__ out, int M, int N, int K) {
  __shared__ __align__(16) int8_t As[TILE * BKB];
  __shared__ __align__(16) int8_t Bs[TILE * BKB];

  const int tid = threadIdx.x;
  const int lane = tid & 63;
  const int wid = tid >> 6;      // 0..3
  const int wr = wid >> 1;       // wave row (2x2 wave grid, 64x64 out per wave)
  const int wc = wid & 1;
  const int row0 = blockIdx.y * TILE;
  const int col0 = blockIdx.x * TILE;

  // staging geometry: one global_load_lds covers 16 rows x 64B; 4 lanes per row
  const int srow = lane >> 2;    // 0..15 row within the 16-row group
  const int sgr  = lane & 3;     // dest granule (linear in LDS)

  v4i acc[4][4];
#pragma unroll
  for (int m = 0; m < 4; ++m)
#pragma unroll
    for (int n = 0; n < 4; ++n) {
      v4i z = {0, 0, 0, 0};
      acc[m][n] = z;
    }

  // fragment LDS byte offsets (constant per thread)
  // frag layout (i8 16x16x64): row = lane&15, k = (lane>>4)*16 + i  -> one b128 read
  int a_off[4], b_off[4];
#pragma unroll
  for (int m = 0; m < 4; ++m) {
    int r = wr * 64 + m * 16 + (lane & 15);
    a_off[m] = r * 64 + ((((lane >> 4)) ^ ((r >> 1) & 3)) << 4);
    int c = wc * 64 + m * 16 + (lane & 15);
    b_off[m] = c * 64 + ((((lane >> 4)) ^ ((c >> 1) & 3)) << 4);
  }

  // staging per-lane row/granule for the 2 instructions per matrix per wave
  int srA[2], sgA[2];
#pragma unroll
  for (int h = 0; h < 2; ++h) {
    int r = wid * 32 + h * 16 + srow;
    srA[h] = r;
    sgA[h] = sgr ^ ((r >> 1) & 3);   // inverse-swizzled SOURCE granule
  }

  for (int k0 = 0; k0 < K; k0 += BKB) {
#pragma unroll
    for (int h = 0; h < 2; ++h) {
      const int rbase = wid * 32 + h * 16;
      __builtin_amdgcn_global_load_lds(
          (const __attribute__((address_space(1))) uint32_t*)
              (A8 + (size_t)(row0 + srA[h]) * K + k0 + sgA[h] * 16),
          (__attribute__((address_space(3))) uint32_t*)(As + rbase * 64),
          16, 0, 0);
      __builtin_amdgcn_global_load_lds(
          (const __attribute__((address_space(1))) uint32_t*)
              (B8 + (size_t)(col0 + srA[h]) * K + k0 + sgA[h] * 16),
          (__attribute__((address_space(3))) uint32_t*)(Bs + rbase * 64),
          16, 0, 0);
    }
    __syncthreads();   // compiler emits vmcnt(0) drain before barrier

    v4i a[4], b[4];
#pragma unroll
    for (int m = 0; m < 4; ++m) a[m] = *(const v4i*)(As + a_off[m]);
#pragma unroll
    for (int n = 0; n < 4; ++n) b[n] = *(const v4i*)(Bs + b_off[n]);
#pragma unroll
    for (int m = 0; m < 4; ++m)
#pragma unroll
      for (int n = 0; n < 4; ++n)
        acc[m][n] = __builtin_amdgcn_mfma_i32_16x16x64_i8(a[m], b[n], acc[m][n], 0, 0, 0);

    __syncthreads();   // compute done before next stage overwrites
  }

  // epilogue: C/D layout (16x16, dtype-independent): col = lane&15, row = (lane>>4)*4 + reg
  const int cw = col0 + wc * 64;
  const int rw = row0 + wr * 64;
  float sc[4], bi[4];
#pragma unroll
  for (int n = 0; n < 4; ++n) {
    int c = cw + n * 16 + (lane & 15);
    sc[n] = scale[c];
    bi[n] = bias[c];
  }
#pragma unroll
  for (int m = 0; m < 4; ++m) {
    int r0 = rw + m * 16 + ((lane >> 4) << 2);
#pragma unroll
    for (int reg = 0; reg < 4; ++reg) {
      float* orow = out + (size_t)(r0 + reg) * N;
#pragma unroll
      for (int n = 0; n < 4; ++n)
        orow[cw + n * 16 + (lane & 15)] = fmaf((float)acc[m][n][reg], sc[n], bi[n]);
    }
  }
}

// ======================= fallback: XOR-popcount GEMM (round-1) =======================
__global__ void pack_sign_bits_kernel(const uint32_t* __restrict__ in,
                                      uint32_t* __restrict__ outp, int nwords) {
  int w = blockIdx.x * blockDim.x + threadIdx.x;
  if (w >= nwords) return;
  const uint4* p = reinterpret_cast<const uint4*>(in) + (size_t)w * 8;
  uint32_t bits = 0;
#pragma unroll
  for (int i = 0; i < 8; ++i) {
    uint4 u = p[i];
    bits |= (u.x >> 31) << (i * 4 + 0);
    bits |= (u.y >> 31) << (i * 4 + 1);
    bits |= (u.z >> 31) << (i * 4 + 2);
    bits |= (u.w >> 31) << (i * 4 + 3);
  }
  outp[w] = bits;
}

#define BM 128
#define BNT 128
#define KS 16
#define TMF 8
#define TNF 8

__global__ __launch_bounds__(256) void popc_gemm_kernel(
    const uint32_t* __restrict__ XP, const uint32_t* __restrict__ WP,
    const float* __restrict__ scale, const float* __restrict__ bias,
    float* __restrict__ out, int Bdim, int OUT, int KW) {
  __shared__ __align__(16) uint32_t xs[KS][BM];
  __shared__ __align__(16) uint32_t wsm[KS][BNT];
  const int tid = threadIdx.x;
  const int tx = tid & 15;
  const int ty = tid >> 4;
  const int row0 = blockIdx.y * BM;
  const int col0 = blockIdx.x * BNT;
  const int lrow = tid >> 1;
  const int h = tid & 1;
  const uint32_t* xg = XP + (size_t)(row0 + lrow) * KW + h * 8;
  const uint32_t* wg = WP + (size_t)(col0 + lrow) * KW + h * 8;
  uint32_t acc[TMF][TNF];
#pragma unroll
  for (int i = 0; i < TMF; ++i)
#pragma unroll
    for (int j = 0; j < TNF; ++j) acc[i][j] = 0u;
  for (int k0 = 0; k0 < KW; k0 += KS) {
    uint4 xv0 = *reinterpret_cast<const uint4*>(xg + k0);
    uint4 xv1 = *reinterpret_cast<const uint4*>(xg + k0 + 4);
    uint4 wv0 = *reinterpret_cast<const uint4*>(wg + k0);
    uint4 wv1 = *reinterpret_cast<const uint4*>(wg + k0 + 4);
    __syncthreads();
    xs[h * 8 + 0][lrow] = xv0.x; xs[h * 8 + 1][lrow] = xv0.y;
    xs[h * 8 + 2][lrow] = xv0.z; xs[h * 8 + 3][lrow] = xv0.w;
    xs[h * 8 + 4][lrow] = xv1.x; xs[h * 8 + 5][lrow] = xv1.y;
    xs[h * 8 + 6][lrow] = xv1.z; xs[h * 8 + 7][lrow] = xv1.w;
    wsm[h * 8 + 0][lrow] = wv0.x; wsm[h * 8 + 1][lrow] = wv0.y;
    wsm[h * 8 + 2][lrow] = wv0.z; wsm[h * 8 + 3][lrow] = wv0.w;
    wsm[h * 8 + 4][lrow] = wv1.x; wsm[h * 8 + 5][lrow] = wv1.y;
    wsm[h * 8 + 6][lrow] = wv1.z; wsm[h * 8 + 7][lrow] = wv1.w;
    __syncthreads();
#pragma unroll 4
    for (int kk = 0; kk < KS; ++kk) {
      uint4 a0 = *reinterpret_cast<const uint4*>(&xs[kk][ty * 8]);
      uint4 a1 = *reinterpret_cast<const uint4*>(&xs[kk][ty * 8 + 4]);
      uint4 b0 = *reinterpret_cast<const uint4*>(&wsm[kk][tx * 4]);
      uint4 b1 = *reinterpret_cast<const uint4*>(&wsm[kk][tx * 4 + 64]);
      uint32_t xr[TMF] = {a0.x, a0.y, a0.z, a0.w, a1.x, a1.y, a1.z, a1.w};
      uint32_t wr[TNF] = {b0.x, b0.y, b0.z, b0.w, b1.x, b1.y, b1.z, b1.w};
#pragma unroll
      for (int i = 0; i < TMF; ++i)
#pragma unroll
        for (int j = 0; j < TNF; ++j)
          acc[i][j] += (uint32_t)__popc(xr[i] ^ wr[j]);
    }
  }
  const float IN_total = (float)(KW * 32);
  float sc[TNF], bi[TNF];
#pragma unroll
  for (int j = 0; j < TNF; ++j) {
    int c = col0 + ((j >> 2) * 64) + tx * 4 + (j & 3);
    sc[j] = scale[c];
    bi[j] = bias[c];
  }
#pragma unroll
  for (int i = 0; i < TMF; ++i) {
    int r = row0 + ty * 8 + i;
    float4 v0, v1;
    v0.x = fmaf(IN_total - 2.0f * (float)acc[i][0], sc[0], bi[0]);
    v0.y = fmaf(IN_total - 2.0f * (float)acc[i][1], sc[1], bi[1]);
    v0.z = fmaf(IN_total - 2.0f * (float)acc[i][2], sc[2], bi[2]);
    v0.w = fmaf(IN_total - 2.0f * (float)acc[i][3], sc[3], bi[3]);
    v1.x = fmaf(IN_total - 2.0f * (float)acc[i][4], sc[4], bi[4]);
    v1.y = fmaf(IN_total - 2.0f * (float)acc[i][5], sc[5], bi[5]);
    v1.z = fmaf(IN_total - 2.0f * (float)acc[i][6], sc[6], bi[6]);
    v1.w = fmaf(IN_total - 2.0f * (float)acc[i][7], sc[7], bi[7]);
    float* orow = out + (size_t)r * OUT;
    *reinterpret_cast<float4*>(orow + col0 + tx * 4) = v0;
    *reinterpret_cast<float4*>(orow + col0 + 64 + tx * 4) = v1;
  }
}

// ======================= launch =======================
extern "C" void kernel_launch(void* const* d_in, const int* in_sizes, int n_in,
                              void* d_out, int out_size, void* d_ws, size_t ws_size,
                              hipStream_t stream) {
  const float* x = (const float*)d_in[0];
  const float* w = (const float*)d_in[1];
  const float* gamma = (const float*)d_in[2];
  const float* beta = (const float*)d_in[3];
  const float* mean = (const float*)d_in[4];
  const float* var = (const float*)d_in[5];
  float* out = (float*)d_out;

  const int OUT = in_sizes[2];            // 4096
  const int IN = in_sizes[1] / OUT;       // 4096
  const int B = in_sizes[0] / IN;         // 8192

  const size_t need_i8 = (size_t)B * IN + (size_t)OUT * IN + 2 * (size_t)OUT * sizeof(float);

  if (ws_size >= need_i8) {
    int8_t* a8 = (int8_t*)d_ws;
    int8_t* b8 = a8 + (size_t)B * IN;
    float* scale = (float*)(b8 + (size_t)OUT * IN);
    float* bias = scale + OUT;

    const int n16x = B * (IN / 16);
    const int n16w = OUT * (IN / 16);
    pack_sign_i8_kernel<<<(n16x + 255) / 256, 256, 0, stream>>>(
        (const uint4*)x, (uint4*)a8, n16x);
    pack_sign_i8_kernel<<<(n16w + 255) / 256, 256, 0, stream>>>(
        (const uint4*)w, (uint4*)b8, n16w);
    bn_prep_kernel<<<(OUT + 255) / 256, 256, 0, stream>>>(
        gamma, beta, mean, var, scale, bias, OUT);

    dim3 grid(OUT / TILE, B / TILE);
    bgemm_i8_kernel<<<grid, 256, 0, stream>>>(a8, b8, scale, bias, out, B, OUT, IN);
  } else {
    const int KW = IN / 32;
    uint32_t* xp = (uint32_t*)d_ws;
    uint32_t* wp = xp + (size_t)B * KW;
    float* scale = (float*)(wp + (size_t)OUT * KW);
    float* bias = scale + OUT;
    const int nwx = B * KW;
    const int nww = OUT * KW;
    pack_sign_bits_kernel<<<(nwx + 255) / 256, 256, 0, stream>>>(
        (const uint32_t*)x, xp, nwx);
    pack_sign_bits_kernel<<<(nww + 255) / 256, 256, 0, stream>>>(
        (const uint32_t*)w, wp, nww);
    bn_prep_kernel<<<(OUT + 255) / 256, 256, 0, stream>>>(
        gamma, beta, mean, var, scale, bias, OUT);
    dim3 grid(OUT / BNT, B / BM);
    popc_gemm_kernel<<<grid, 256, 0, stream>>>(xp, wp, scale, bias, out, B, OUT, KW);
  }
}

// Round 3
// 187.214 us; speedup vs baseline: 2.4537x; 1.2090x over previous
//
#include <hip/hip_runtime.h>
#include <stdint.h>
#include <stddef.h>

// BinarizeLinearWithFoldedBN on MI355X (gfx950).
// out[b,o] = dot(sign(x[b,:]), sign(w[o,:])) * scale[o] + bias[o]
//   scale = gamma/sqrt(var+eps), bias = beta - mean*scale (exact BN algebra)
// i8 (+1/-1) MFMA GEMM, 256x256 tile, 8-wave, 8-phase counted-vmcnt schedule
// (T1 XCD swizzle + T3/T4 phase pipeline + T5 setprio). Exact i32 dot.

#define BN_EPS 1e-5f
typedef int v4i __attribute__((ext_vector_type(4)));

// ---------------- BN fold ----------------
__global__ void bn_prep_kernel(const float* __restrict__ g, const float* __restrict__ b,
                               const float* __restrict__ m, const float* __restrict__ v,
                               float* __restrict__ scale, float* __restrict__ bias, int n) {
  int i = blockIdx.x * blockDim.x + threadIdx.x;
  if (i >= n) return;
  float s = g[i] * rsqrtf(v[i] + BN_EPS);
  scale[i] = s;
  bias[i] = b[i] - m[i] * s;
}

// ---------------- pack f32 signs -> i8 +1/-1 (16 floats -> 16 bytes per thread) ----
__global__ __launch_bounds__(256) void pack_sign_i8_kernel(
    const uint4* __restrict__ in, uint4* __restrict__ outp, int n16) {
  int t = blockIdx.x * blockDim.x + threadIdx.x;
  if (t >= n16) return;
  const uint4* p = in + (size_t)t * 4;
  uint32_t w[4];
#pragma unroll
  for (int i = 0; i < 4; ++i) {
    uint4 u = p[i];
    uint32_t m = (((uint32_t)((int)u.x >> 31)) & 0xFEu)
               | ((((uint32_t)((int)u.y >> 31)) & 0xFEu) << 8)
               | ((((uint32_t)((int)u.z >> 31)) & 0xFEu) << 16)
               | ((((uint32_t)((int)u.w >> 31)) & 0xFEu) << 24);
    w[i] = 0x01010101u ^ m;
  }
  uint4 o; o.x = w[0]; o.y = w[1]; o.z = w[2]; o.w = w[3];
  outp[t] = o;
}

// ---------------- i8 MFMA GEMM: 256x256 tile, 8 waves, 8-phase schedule ----------
// LDS (128 KiB): buf in {0,1}: A(buf,s) at buf*65536 + s*16384   (s = k-slab 0/1)
//                              B(buf,s) at buf*65536 + 32768 + s*16384
// slab = 256 rows x 64 B (one MFMA k-step), row-major, linear (naturally
// bank-balanced for the 16-row x 4-chunk ds_read_b128 fragment pattern).
// K-tile = 128 B. Per tile: 4 phases (kk, mh); 16 MFMA each; 2 global_load_lds
// prefetch per phase (one slab of tile t+1); vmcnt(4) at phase 2 & 4 ends.

#define BAR() asm volatile("s_barrier" ::: "memory")
#define WAITV4() asm volatile("s_waitcnt vmcnt(4)" ::: "memory")
#define WAITV0() asm volatile("s_waitcnt vmcnt(0)" ::: "memory")
#define LGKM0() asm volatile("s_waitcnt lgkmcnt(0)" ::: "memory")
#define SCHED0() __builtin_amdgcn_sched_barrier(0)

__global__ __launch_bounds__(512, 2) void bgemm_i8_8ph(
    const int8_t* __restrict__ A8, const int8_t* __restrict__ B8,
    const float* __restrict__ scale, const float* __restrict__ bias,
    float* __restrict__ out, int M, int N, int K) {
  __shared__ __align__(16) int8_t lds[131072];

  const int tid = threadIdx.x;
  const int lane = tid & 63;
  const int wid = tid >> 6;      // 0..7
  const int wm = wid >> 2;       // 0..1  (128-row band)
  const int wn = wid & 3;        // 0..3  (64-col band)

  // T1: bijective XCD swizzle (nwg % 8 == 0 here: 32*16 = 512)
  const int nbx = N >> 8;
  const int nwg = (M >> 8) * nbx;
  const int cpx = nwg >> 3;
  const int bid = (int)blockIdx.x;
  const int swz = (bid & 7) * cpx + (bid >> 3);
  const int row0 = (swz / nbx) << 8;
  const int col0 = (swz % nbx) << 8;

  const int ln15 = lane & 15;
  const int kc = (lane >> 4) << 4;          // fragment k-chunk byte offset
  const int arow = wm * 128 + ln15;         // + mh*64 + m*16
  const int brow = wn * 64 + ln15;          // + n*16
  const int srow = wid * 16 + (lane >> 2);  // staging row (h=1 adds 128)
  const int sch = (lane & 3) << 4;          // staging chunk byte
  const int ldw = wid << 10;                // wave slot in 8KB half-slab

  const size_t rstr = (size_t)128 * K;
  const int8_t* aSt = A8 + (size_t)(row0 + srow) * K + sch;  // tile-to-stage base
  const int8_t* bSt = B8 + (size_t)(col0 + srow) * K + sch;

  v4i acc[8][4];
#pragma unroll
  for (int i = 0; i < 8; ++i)
#pragma unroll
    for (int n = 0; n < 4; ++n) { v4i z = {0, 0, 0, 0}; acc[i][n] = z; }

  v4i a0, a1, a2, a3, b0, b1, b2, b3;

#define STAGE_A(nb, s) do {                                                           \
  __builtin_amdgcn_global_load_lds(                                                   \
      (const __attribute__((address_space(1))) uint32_t*)(aSt + (s) * 64),            \
      (__attribute__((address_space(3))) uint32_t*)(lds + (nb) * 65536 + (s) * 16384 + ldw), \
      16, 0, 0);                                                                      \
  __builtin_amdgcn_global_load_lds(                                                   \
      (const __attribute__((address_space(1))) uint32_t*)(aSt + rstr + (s) * 64),     \
      (__attribute__((address_space(3))) uint32_t*)(lds + (nb) * 65536 + (s) * 16384 + 8192 + ldw), \
      16, 0, 0);                                                                      \
} while (0)

#define STAGE_B(nb, s) do {                                                           \
  __builtin_amdgcn_global_load_lds(                                                   \
      (const __attribute__((address_space(1))) uint32_t*)(bSt + (s) * 64),            \
      (__attribute__((address_space(3))) uint32_t*)(lds + (nb) * 65536 + 32768 + (s) * 16384 + ldw), \
      16, 0, 0);                                                                      \
  __builtin_amdgcn_global_load_lds(                                                   \
      (const __attribute__((address_space(1))) uint32_t*)(bSt + rstr + (s) * 64),     \
      (__attribute__((address_space(3))) uint32_t*)(lds + (nb) * 65536 + 32768 + (s) * 16384 + 8192 + ldw), \
      16, 0, 0);                                                                      \
} while (0)

#define READ_A(buf, s, mh) do {                                                       \
  const int8_t* ap_ = lds + (buf) * 65536 + (s) * 16384 + (arow + (mh) * 64) * 64 + kc; \
  a0 = *(const v4i*)(ap_);        a1 = *(const v4i*)(ap_ + 1024);                     \
  a2 = *(const v4i*)(ap_ + 2048); a3 = *(const v4i*)(ap_ + 3072);                     \
} while (0)

#define READ_B(buf, s) do {                                                           \
  const int8_t* bp_ = lds + (buf) * 65536 + 32768 + (s) * 16384 + brow * 64 + kc;     \
  b0 = *(const v4i*)(bp_);        b1 = *(const v4i*)(bp_ + 1024);                     \
  b2 = *(const v4i*)(bp_ + 2048); b3 = *(const v4i*)(bp_ + 3072);                     \
} while (0)

#define MFMA16(mh) do {                                                               \
  __builtin_amdgcn_s_setprio(1);                                                      \
  acc[(mh)*4+0][0] = __builtin_amdgcn_mfma_i32_16x16x64_i8(a0, b0, acc[(mh)*4+0][0], 0,0,0); \
  acc[(mh)*4+1][0] = __builtin_amdgcn_mfma_i32_16x16x64_i8(a1, b0, acc[(mh)*4+1][0], 0,0,0); \
  acc[(mh)*4+2][0] = __builtin_amdgcn_mfma_i32_16x16x64_i8(a2, b0, acc[(mh)*4+2][0], 0,0,0); \
  acc[(mh)*4+3][0] = __builtin_amdgcn_mfma_i32_16x16x64_i8(a3, b0, acc[(mh)*4+3][0], 0,0,0); \
  acc[(mh)*4+0][1] = __builtin_amdgcn_mfma_i32_16x16x64_i8(a0, b1, acc[(mh)*4+0][1], 0,0,0); \
  acc[(mh)*4+1][1] = __builtin_amdgcn_mfma_i32_16x16x64_i8(a1, b1, acc[(mh)*4+1][1], 0,0,0); \
  acc[(mh)*4+2][1] = __builtin_amdgcn_mfma_i32_16x16x64_i8(a2, b1, acc[(mh)*4+2][1], 0,0,0); \
  acc[(mh)*4+3][1] = __builtin_amdgcn_mfma_i32_16x16x64_i8(a3, b1, acc[(mh)*4+3][1], 0,0,0); \
  acc[(mh)*4+0][2] = __builtin_amdgcn_mfma_i32_16x16x64_i8(a0, b2, acc[(mh)*4+0][2], 0,0,0); \
  acc[(mh)*4+1][2] = __builtin_amdgcn_mfma_i32_16x16x64_i8(a1, b2, acc[(mh)*4+1][2], 0,0,0); \
  acc[(mh)*4+2][2] = __builtin_amdgcn_mfma_i32_16x16x64_i8(a2, b2, acc[(mh)*4+2][2], 0,0,0); \
  acc[(mh)*4+3][2] = __builtin_amdgcn_mfma_i32_16x16x64_i8(a3, b2, acc[(mh)*4+3][2], 0,0,0); \
  acc[(mh)*4+0][3] = __builtin_amdgcn_mfma_i32_16x16x64_i8(a0, b3, acc[(mh)*4+0][3], 0,0,0); \
  acc[(mh)*4+1][3] = __builtin_amdgcn_mfma_i32_16x16x64_i8(a1, b3, acc[(mh)*4+1][3], 0,0,0); \
  acc[(mh)*4+2][3] = __builtin_amdgcn_mfma_i32_16x16x64_i8(a2, b3, acc[(mh)*4+2][3], 0,0,0); \
  acc[(mh)*4+3][3] = __builtin_amdgcn_mfma_i32_16x16x64_i8(a3, b3, acc[(mh)*4+3][3], 0,0,0); \
  __builtin_amdgcn_s_setprio(0);                                                      \
} while (0)

  const int NT = K >> 7;   // K-tiles of 128 B

  // ---- prologue: stage tile 0 into buf 0 (8 loads), complete slab 0, keep slab 1 in flight
  STAGE_A(0, 0); STAGE_B(0, 0); STAGE_A(0, 1); STAGE_B(0, 1);
  aSt += 128; bSt += 128;
  WAITV4();
  BAR();

  // ---- main loop: compute tile t from buf (t&1), stage tile t+1 into buf^1
  for (int t = 0; t < NT - 1; ++t) {
    const int buf = t & 1;
    const int nb = buf ^ 1;
    // P1 (kk=0, mh=0)
    READ_A(buf, 0, 0); READ_B(buf, 0);
    STAGE_A(nb, 0);
    BAR(); LGKM0(); SCHED0();
    MFMA16(0);
    BAR();
    // P2 (kk=0, mh=1)
    READ_A(buf, 0, 1);
    STAGE_B(nb, 0);
    BAR(); LGKM0(); SCHED0();
    MFMA16(1);
    WAITV4();   // completes this tile's slab-1 loads (issued last tile P3/P4)
    BAR();
    // P3 (kk=1, mh=0)
    READ_A(buf, 1, 0); READ_B(buf, 1);
    STAGE_A(nb, 1);
    BAR(); LGKM0(); SCHED0();
    MFMA16(0);
    BAR();
    // P4 (kk=1, mh=1)
    READ_A(buf, 1, 1);
    STAGE_B(nb, 1);
    BAR(); LGKM0(); SCHED0();
    MFMA16(1);
    WAITV4();   // completes next tile's slab-0 loads (issued at P1/P2)
    BAR();
    aSt += 128; bSt += 128;
  }

  // ---- peeled last tile (no staging; single drain allowed in epilogue)
  {
    const int buf = (NT - 1) & 1;
    READ_A(buf, 0, 0); READ_B(buf, 0);
    BAR(); LGKM0(); SCHED0();
    MFMA16(0);
    BAR();
    READ_A(buf, 0, 1);
    BAR(); LGKM0(); SCHED0();
    MFMA16(1);
    WAITV0();   // drain slab-1 loads
    BAR();
    READ_A(buf, 1, 0); READ_B(buf, 1);
    BAR(); LGKM0(); SCHED0();
    MFMA16(0);
    BAR();
    READ_A(buf, 1, 1);
    BAR(); LGKM0(); SCHED0();
    MFMA16(1);
  }

  // ---- epilogue: C/D layout col = lane&15, row = (lane>>4)*4 + reg; acc[i] <-> rows wm*128+i*16
  const int cw = col0 + wn * 64;
  float scv[4], biv[4];
#pragma unroll
  for (int n = 0; n < 4; ++n) {
    int c = cw + n * 16 + ln15;
    scv[n] = scale[c];
    biv[n] = bias[c];
  }
#pragma unroll
  for (int i = 0; i < 8; ++i) {
    const int r0 = row0 + wm * 128 + i * 16 + ((lane >> 4) << 2);
#pragma unroll
    for (int reg = 0; reg < 4; ++reg) {
      float* orow = out + (size_t)(r0 + reg) * N;
#pragma unroll
      for (int n = 0; n < 4; ++n)
        orow[cw + n * 16 + ln15] = fmaf((float)acc[i][n][reg], scv[n], biv[n]);
    }
  }

#undef STAGE_A
#undef STAGE_B
#undef READ_A
#undef READ_B
#undef MFMA16
}

// ======================= launch =======================
extern "C" void kernel_launch(void* const* d_in, const int* in_sizes, int n_in,
                              void* d_out, int out_size, void* d_ws, size_t ws_size,
                              hipStream_t stream) {
  const float* x = (const float*)d_in[0];
  const float* w = (const float*)d_in[1];
  const float* gamma = (const float*)d_in[2];
  const float* beta = (const float*)d_in[3];
  const float* mean = (const float*)d_in[4];
  const float* var = (const float*)d_in[5];
  float* out = (float*)d_out;

  const int OUT = in_sizes[2];            // 4096
  const int IN = in_sizes[1] / OUT;       // 4096
  const int B = in_sizes[0] / IN;         // 8192

  int8_t* a8 = (int8_t*)d_ws;
  int8_t* b8 = a8 + (size_t)B * IN;
  float* scale = (float*)(b8 + (size_t)OUT * IN);
  float* bias = scale + OUT;

  const int n16x = B * (IN / 16);
  const int n16w = OUT * (IN / 16);
  pack_sign_i8_kernel<<<(n16x + 255) / 256, 256, 0, stream>>>(
      (const uint4*)x, (uint4*)a8, n16x);
  pack_sign_i8_kernel<<<(n16w + 255) / 256, 256, 0, stream>>>(
      (const uint4*)w, (uint4*)b8, n16w);
  bn_prep_kernel<<<(OUT + 255) / 256, 256, 0, stream>>>(
      gamma, beta, mean, var, scale, bias, OUT);

  dim3 grid((B >> 8) * (OUT >> 8));
  bgemm_i8_8ph<<<grid, 512, 0, stream>>>(a8, b8, scale, bias, out, B, OUT, IN);
}

// Round 4
// 182.281 us; speedup vs baseline: 2.5201x; 1.0271x over previous
//
#include <hip/hip_runtime.h>
#include <stdint.h>
#include <stddef.h>

// BinarizeLinearWithFoldedBN on MI355X (gfx950).
// out[b,o] = dot(sign(x[b,:]), sign(w[o,:])) * scale[o] + bias[o]
//   scale = gamma/sqrt(var+eps), bias = beta - mean*scale (exact BN algebra)
// i8 (+1/-1) MFMA GEMM, 256x256 tile, 8-wave, 8-phase counted-vmcnt schedule
// (T1 XCD swizzle + T2 granule swizzle + T3/T4 pipeline + T5 setprio). Exact i32 dot.

#define BN_EPS 1e-5f
typedef int v4i __attribute__((ext_vector_type(4)));

// ---------------- BN fold ----------------
__global__ void bn_prep_kernel(const float* __restrict__ g, const float* __restrict__ b,
                               const float* __restrict__ m, const float* __restrict__ v,
                               float* __restrict__ scale, float* __restrict__ bias, int n) {
  int i = blockIdx.x * blockDim.x + threadIdx.x;
  if (i >= n) return;
  float s = g[i] * rsqrtf(v[i] + BN_EPS);
  scale[i] = s;
  bias[i] = b[i] - m[i] * s;
}

// ---------------- pack f32 signs -> i8 +1/-1 (16 floats -> 16 bytes per thread) ----
__global__ __launch_bounds__(256) void pack_sign_i8_kernel(
    const uint4* __restrict__ in, uint4* __restrict__ outp, int n16) {
  int t = blockIdx.x * blockDim.x + threadIdx.x;
  if (t >= n16) return;
  const uint4* p = in + (size_t)t * 4;
  uint32_t w[4];
#pragma unroll
  for (int i = 0; i < 4; ++i) {
    uint4 u = p[i];
    uint32_t m = (((uint32_t)((int)u.x >> 31)) & 0xFEu)
               | ((((uint32_t)((int)u.y >> 31)) & 0xFEu) << 8)
               | ((((uint32_t)((int)u.z >> 31)) & 0xFEu) << 16)
               | ((((uint32_t)((int)u.w >> 31)) & 0xFEu) << 24);
    w[i] = 0x01010101u ^ m;
  }
  uint4 o; o.x = w[0]; o.y = w[1]; o.z = w[2]; o.w = w[3];
  outp[t] = o;
}

// ---------------- i8 MFMA GEMM: 256x256 tile, 8 waves, 8-phase schedule ----------
// LDS (128 KiB): buf in {0,1}: A(buf,s) at buf*65536 + s*16384   (s = k-slab 0/1)
//                              B(buf,s) at buf*65536 + 32768 + s*16384
// slab = 256 rows x 64 B, row-major, 16B-granule XOR swizzle:
//   LDS(row R, chunk C) holds global granule C ^ ((R>>1)&3) of row R.
//   Staged via linear gload_lds dest + pre-swizzled SOURCE granule (rule #21);
//   fragment reads use chunk = (lane>>4) ^ ((ln15>>1)&3)  -> conflict-free b128.
// K-tile = 128 B. Per tile: 4 phases (kk, mh); 16 MFMA each; 2 global_load_lds
// prefetch per phase (one slab of tile t+1); vmcnt(4) at phase 2 & 4 ends.

#define BAR() asm volatile("s_barrier" ::: "memory")
#define WAITV4() asm volatile("s_waitcnt vmcnt(4)" ::: "memory")
#define WAITV0() asm volatile("s_waitcnt vmcnt(0)" ::: "memory")
#define LGKM0() asm volatile("s_waitcnt lgkmcnt(0)" ::: "memory")
#define SCHED0() __builtin_amdgcn_sched_barrier(0)

__global__ __launch_bounds__(512, 2) void bgemm_i8_8ph(
    const int8_t* __restrict__ A8, const int8_t* __restrict__ B8,
    const float* __restrict__ scale, const float* __restrict__ bias,
    float* __restrict__ out, int M, int N, int K) {
  __shared__ __align__(16) int8_t lds[131072];

  const int tid = threadIdx.x;
  const int lane = tid & 63;
  const int wid = tid >> 6;      // 0..7
  const int wm = wid >> 2;       // 0..1  (128-row band)
  const int wn = wid & 3;        // 0..3  (64-col band)

  // T1: bijective XCD swizzle (nwg % 8 == 0 here: 32*16 = 512)
  const int nbx = N >> 8;
  const int nwg = (M >> 8) * nbx;
  const int cpx = nwg >> 3;
  const int bid = (int)blockIdx.x;
  const int swz = (bid & 7) * cpx + (bid >> 3);
  const int row0 = (swz / nbx) << 8;
  const int col0 = (swz % nbx) << 8;

  const int ln15 = lane & 15;
  // T2 read-side swizzle: fragment k-chunk byte offset
  const int kcs = (((lane >> 4) ^ ((ln15 >> 1) & 3)) << 4);
  const int arow = wm * 128 + ln15;         // + mh*64 + m*16
  const int brow = wn * 64 + ln15;          // + n*16
  const int srow = wid * 16 + (lane >> 2);  // staging row (2nd inst adds 128)
  // T2 write-side: pre-swizzled SOURCE granule (dest row bits (lane>>3)&3)
  const int sch = (((lane & 3) ^ ((lane >> 3) & 3)) << 4);
  const int ldw = wid << 10;                // wave slot in 8KB half-slab

  const size_t rstr = (size_t)128 * K;
  const int8_t* aSt = A8 + (size_t)(row0 + srow) * K + sch;  // tile-to-stage base
  const int8_t* bSt = B8 + (size_t)(col0 + srow) * K + sch;

  v4i acc[8][4];
#pragma unroll
  for (int i = 0; i < 8; ++i)
#pragma unroll
    for (int n = 0; n < 4; ++n) { v4i z = {0, 0, 0, 0}; acc[i][n] = z; }

  v4i a0, a1, a2, a3, b0, b1, b2, b3;

#define STAGE_A(nb, s) do {                                                           \
  __builtin_amdgcn_global_load_lds(                                                   \
      (const __attribute__((address_space(1))) uint32_t*)(aSt + (s) * 64),            \
      (__attribute__((address_space(3))) uint32_t*)(lds + (nb) * 65536 + (s) * 16384 + ldw), \
      16, 0, 0);                                                                      \
  __builtin_amdgcn_global_load_lds(                                                   \
      (const __attribute__((address_space(1))) uint32_t*)(aSt + rstr + (s) * 64),     \
      (__attribute__((address_space(3))) uint32_t*)(lds + (nb) * 65536 + (s) * 16384 + 8192 + ldw), \
      16, 0, 0);                                                                      \
} while (0)

#define STAGE_B(nb, s) do {                                                           \
  __builtin_amdgcn_global_load_lds(                                                   \
      (const __attribute__((address_space(1))) uint32_t*)(bSt + (s) * 64),            \
      (__attribute__((address_space(3))) uint32_t*)(lds + (nb) * 65536 + 32768 + (s) * 16384 + ldw), \
      16, 0, 0);                                                                      \
  __builtin_amdgcn_global_load_lds(                                                   \
      (const __attribute__((address_space(1))) uint32_t*)(bSt + rstr + (s) * 64),     \
      (__attribute__((address_space(3))) uint32_t*)(lds + (nb) * 65536 + 32768 + (s) * 16384 + 8192 + ldw), \
      16, 0, 0);                                                                      \
} while (0)

#define READ_A(buf, s, mh) do {                                                       \
  const int8_t* ap_ = lds + (buf) * 65536 + (s) * 16384 + (arow + (mh) * 64) * 64 + kcs; \
  a0 = *(const v4i*)(ap_);        a1 = *(const v4i*)(ap_ + 1024);                     \
  a2 = *(const v4i*)(ap_ + 2048); a3 = *(const v4i*)(ap_ + 3072);                     \
} while (0)

#define READ_B(buf, s) do {                                                           \
  const int8_t* bp_ = lds + (buf) * 65536 + 32768 + (s) * 16384 + brow * 64 + kcs;    \
  b0 = *(const v4i*)(bp_);        b1 = *(const v4i*)(bp_ + 1024);                     \
  b2 = *(const v4i*)(bp_ + 2048); b3 = *(const v4i*)(bp_ + 3072);                     \
} while (0)

#define MFMA16(mh) do {                                                               \
  __builtin_amdgcn_s_setprio(1);                                                      \
  acc[(mh)*4+0][0] = __builtin_amdgcn_mfma_i32_16x16x64_i8(a0, b0, acc[(mh)*4+0][0], 0,0,0); \
  acc[(mh)*4+1][0] = __builtin_amdgcn_mfma_i32_16x16x64_i8(a1, b0, acc[(mh)*4+1][0], 0,0,0); \
  acc[(mh)*4+2][0] = __builtin_amdgcn_mfma_i32_16x16x64_i8(a2, b0, acc[(mh)*4+2][0], 0,0,0); \
  acc[(mh)*4+3][0] = __builtin_amdgcn_mfma_i32_16x16x64_i8(a3, b0, acc[(mh)*4+3][0], 0,0,0); \
  acc[(mh)*4+0][1] = __builtin_amdgcn_mfma_i32_16x16x64_i8(a0, b1, acc[(mh)*4+0][1], 0,0,0); \
  acc[(mh)*4+1][1] = __builtin_amdgcn_mfma_i32_16x16x64_i8(a1, b1, acc[(mh)*4+1][1], 0,0,0); \
  acc[(mh)*4+2][1] = __builtin_amdgcn_mfma_i32_16x16x64_i8(a2, b1, acc[(mh)*4+2][1], 0,0,0); \
  acc[(mh)*4+3][1] = __builtin_amdgcn_mfma_i32_16x16x64_i8(a3, b1, acc[(mh)*4+3][1], 0,0,0); \
  acc[(mh)*4+0][2] = __builtin_amdgcn_mfma_i32_16x16x64_i8(a0, b2, acc[(mh)*4+0][2], 0,0,0); \
  acc[(mh)*4+1][2] = __builtin_amdgcn_mfma_i32_16x16x64_i8(a1, b2, acc[(mh)*4+1][2], 0,0,0); \
  acc[(mh)*4+2][2] = __builtin_amdgcn_mfma_i32_16x16x64_i8(a2, b2, acc[(mh)*4+2][2], 0,0,0); \
  acc[(mh)*4+3][2] = __builtin_amdgcn_mfma_i32_16x16x64_i8(a3, b2, acc[(mh)*4+3][2], 0,0,0); \
  acc[(mh)*4+0][3] = __builtin_amdgcn_mfma_i32_16x16x64_i8(a0, b3, acc[(mh)*4+0][3], 0,0,0); \
  acc[(mh)*4+1][3] = __builtin_amdgcn_mfma_i32_16x16x64_i8(a1, b3, acc[(mh)*4+1][3], 0,0,0); \
  acc[(mh)*4+2][3] = __builtin_amdgcn_mfma_i32_16x16x64_i8(a2, b3, acc[(mh)*4+2][3], 0,0,0); \
  acc[(mh)*4+3][3] = __builtin_amdgcn_mfma_i32_16x16x64_i8(a3, b3, acc[(mh)*4+3][3], 0,0,0); \
  __builtin_amdgcn_s_setprio(0);                                                      \
} while (0)

  const int NT = K >> 7;   // K-tiles of 128 B

  // ---- prologue: stage tile 0 into buf 0 (8 loads), complete slab 0, keep slab 1 in flight
  STAGE_A(0, 0); STAGE_B(0, 0); STAGE_A(0, 1); STAGE_B(0, 1);
  aSt += 128; bSt += 128;
  WAITV4();
  BAR();

  // ---- main loop: compute tile t from buf (t&1), stage tile t+1 into buf^1
  for (int t = 0; t < NT - 1; ++t) {
    const int buf = t & 1;
    const int nb = buf ^ 1;
    // P1 (kk=0, mh=0)
    READ_A(buf, 0, 0); READ_B(buf, 0);
    STAGE_A(nb, 0);
    BAR(); LGKM0(); SCHED0();
    MFMA16(0);
    BAR();
    // P2 (kk=0, mh=1)
    READ_A(buf, 0, 1);
    STAGE_B(nb, 0);
    BAR(); LGKM0(); SCHED0();
    MFMA16(1);
    WAITV4();   // completes this tile's slab-1 loads (issued last tile P3/P4)
    BAR();
    // P3 (kk=1, mh=0)
    READ_A(buf, 1, 0); READ_B(buf, 1);
    STAGE_A(nb, 1);
    BAR(); LGKM0(); SCHED0();
    MFMA16(0);
    BAR();
    // P4 (kk=1, mh=1)
    READ_A(buf, 1, 1);
    STAGE_B(nb, 1);
    BAR(); LGKM0(); SCHED0();
    MFMA16(1);
    WAITV4();   // completes next tile's slab-0 loads (issued at P1/P2)
    BAR();
    aSt += 128; bSt += 128;
  }

  // ---- peeled last tile (no staging; single drain allowed in epilogue)
  {
    const int buf = (NT - 1) & 1;
    READ_A(buf, 0, 0); READ_B(buf, 0);
    BAR(); LGKM0(); SCHED0();
    MFMA16(0);
    BAR();
    READ_A(buf, 0, 1);
    BAR(); LGKM0(); SCHED0();
    MFMA16(1);
    WAITV0();   // drain slab-1 loads
    BAR();
    READ_A(buf, 1, 0); READ_B(buf, 1);
    BAR(); LGKM0(); SCHED0();
    MFMA16(0);
    BAR();
    READ_A(buf, 1, 1);
    BAR(); LGKM0(); SCHED0();
    MFMA16(1);
  }

  // ---- epilogue: C/D layout col = lane&15, row = (lane>>4)*4 + reg; acc[i] <-> rows wm*128+i*16
  const int cw = col0 + wn * 64;
  float scv[4], biv[4];
#pragma unroll
  for (int n = 0; n < 4; ++n) {
    int c = cw + n * 16 + ln15;
    scv[n] = scale[c];
    biv[n] = bias[c];
  }
#pragma unroll
  for (int i = 0; i < 8; ++i) {
    const int r0 = row0 + wm * 128 + i * 16 + ((lane >> 4) << 2);
#pragma unroll
    for (int reg = 0; reg < 4; ++reg) {
      float* orow = out + (size_t)(r0 + reg) * N;
#pragma unroll
      for (int n = 0; n < 4; ++n)
        orow[cw + n * 16 + ln15] = fmaf((float)acc[i][n][reg], scv[n], biv[n]);
    }
  }

#undef STAGE_A
#undef STAGE_B
#undef READ_A
#undef READ_B
#undef MFMA16
}

// ======================= launch =======================
extern "C" void kernel_launch(void* const* d_in, const int* in_sizes, int n_in,
                              void* d_out, int out_size, void* d_ws, size_t ws_size,
                              hipStream_t stream) {
  const float* x = (const float*)d_in[0];
  const float* w = (const float*)d_in[1];
  const float* gamma = (const float*)d_in[2];
  const float* beta = (const float*)d_in[3];
  const float* mean = (const float*)d_in[4];
  const float* var = (const float*)d_in[5];
  float* out = (float*)d_out;

  const int OUT = in_sizes[2];            // 4096
  const int IN = in_sizes[1] / OUT;       // 4096
  const int B = in_sizes[0] / IN;         // 8192

  int8_t* a8 = (int8_t*)d_ws;
  int8_t* b8 = a8 + (size_t)B * IN;
  float* scale = (float*)(b8 + (size_t)OUT * IN);
  float* bias = scale + OUT;

  const int n16x = B * (IN / 16);
  const int n16w = OUT * (IN / 16);
  pack_sign_i8_kernel<<<(n16x + 255) / 256, 256, 0, stream>>>(
      (const uint4*)x, (uint4*)a8, n16x);
  pack_sign_i8_kernel<<<(n16w + 255) / 256, 256, 0, stream>>>(
      (const uint4*)w, (uint4*)b8, n16w);
  bn_prep_kernel<<<(OUT + 255) / 256, 256, 0, stream>>>(
      gamma, beta, mean, var, scale, bias, OUT);

  dim3 grid((B >> 8) * (OUT >> 8));
  bgemm_i8_8ph<<<grid, 512, 0, stream>>>(a8, b8, scale, bias, out, B, OUT, IN);
}